// Round 1
// baseline (86.066 us; speedup 1.0000x reference)
//
#include <hip/hip_runtime.h>
#include <hip/hip_bf16.h>

// Encoder: B=16, H*W=n=1024, C=256, K=32, fp32.
// enc[b,k,c] = S1[b,k,c] - wsum[b,k]*cw[k,c];  S1 = sum_n w*x, wsum = sum_n w
// w = softmax_k( sf[k] * ||x_n - cw_k||^2 )
// out[b,c] = sum_k relu( (enc - mean_c)*rsqrt(var_c+1e-3)*gamma + beta )

#define BN_EPS 1e-3f

template<int BPB>
__global__ __launch_bounds__(256, 2) void enc_main(
    const float* __restrict__ x, const float* __restrict__ cw,
    const float* __restrict__ sf, float* __restrict__ pS1, float* __restrict__ pW)
{
    constexpr int POSB = 1024 / BPB;   // positions per block
    constexpr int PPW  = POSB / 4;     // positions per wave
    constexpr int PAIRS = PPW / 2;

    const int b = blockIdx.x / BPB;
    const int j = blockIdx.x % BPB;
    const int t = threadIdx.x;
    const int w = t >> 6;
    const int lane = t & 63;
    const int h = lane >> 5;     // which position of the pair this lane scores
    const int k = lane & 31;     // codeword index

    // cw staged as float4[32][65] (row stride 65 chunks = 260 words -> 4k mod 32
    // spreads consecutive lanes across banks for ds_read_b128). Reused as the
    // accumulator merge buffer after the pair loop (cw is dead by then).
    __shared__ float4 cwacc[32][65];
    __shared__ float4 xs4[4][2][64];   // per-wave staging of the 2 positions
    __shared__ float  wsum_lds[4][32];

    for (int i = t; i < 2048; i += 256) {
        cwacc[i >> 6][i & 63] = ((const float4*)cw)[i];
    }
    const float sfk = sf[k];
    __syncthreads();

    float4 acc[32];                    // lane-owned S1 accumulator: k x 128 channels
    #pragma unroll
    for (int i = 0; i < 32; ++i) acc[i] = make_float4(0.f, 0.f, 0.f, 0.f);
    float wsum = 0.f;

    const float* xb = x + (size_t)b * 1024 * 256;
    const int nbase = j * POSB + w * PPW;

    #pragma unroll 1
    for (int pr = 0; pr < PAIRS; ++pr) {
        const int n0 = nbase + pr * 2;
        float4 v0 = ((const float4*)(xb + (size_t)n0 * 256))[lane];
        float4 v1 = ((const float4*)(xb + (size_t)(n0 + 1) * 256))[lane];
        xs4[w][0][lane] = v0;
        xs4[w][1][lane] = v1;
        // wave-private LDS region: compiler-inserted lgkmcnt suffices, no barrier

        float sq0 = 0.f, sq1 = 0.f, sq2 = 0.f, sq3 = 0.f;
        #pragma unroll
        for (int ci = 0; ci < 64; ++ci) {
            float4 cv = cwacc[k][ci];
            float4 xv = xs4[w][h][ci];
            float d0 = xv.x - cv.x, d1 = xv.y - cv.y;
            float d2 = xv.z - cv.z, d3 = xv.w - cv.w;
            sq0 = fmaf(d0, d0, sq0); sq1 = fmaf(d1, d1, sq1);
            sq2 = fmaf(d2, d2, sq2); sq3 = fmaf(d3, d3, sq3);
        }
        float s = sfk * ((sq0 + sq1) + (sq2 + sq3));

        // softmax over 32 codewords within each half-wave (xor<=16 stays in half)
        float m = s;
        #pragma unroll
        for (int d = 1; d <= 16; d <<= 1) m = fmaxf(m, __shfl_xor(m, d, 64));
        float e = __expf(s - m);
        float ssum = e;
        #pragma unroll
        for (int d = 1; d <= 16; d <<= 1) ssum += __shfl_xor(ssum, d, 64);
        float wgt = e / ssum;
        wsum += wgt;

        float wo = __shfl_xor(wgt, 32, 64);  // same k, other position
        float w0 = h ? wo : wgt;             // weight of pair-position 0 for this k
        float w1 = h ? wgt : wo;

        // accumulate w0*x0 + w1*x1 into registers; lane owns channels [h*128, h*128+128)
        #pragma unroll
        for (int i = 0; i < 32; ++i) {
            float4 x0 = xs4[w][0][h * 32 + i];
            float4 x1 = xs4[w][1][h * 32 + i];
            acc[i].x = fmaf(w0, x0.x, fmaf(w1, x1.x, acc[i].x));
            acc[i].y = fmaf(w0, x0.y, fmaf(w1, x1.y, acc[i].y));
            acc[i].z = fmaf(w0, x0.z, fmaf(w1, x1.z, acc[i].z));
            acc[i].w = fmaf(w0, x0.w, fmaf(w1, x1.w, acc[i].w));
        }
    }

    float wtot = wsum + __shfl_xor(wsum, 32, 64);
    if (h == 0) wsum_lds[w][k] = wtot;
    __syncthreads();   // all waves done with cw reads; cwacc becomes merge buffer

    // staggered conflict-free merge: round r, wave w owns k-quarter (w+r)&3
    #pragma unroll
    for (int r = 0; r < 4; ++r) {
        const int q = (w + r) & 3;
        if ((k >> 3) == q) {
            #pragma unroll
            for (int i = 0; i < 32; ++i) {
                if (r == 0) {
                    cwacc[k][h * 32 + i] = acc[i];
                } else {
                    float4 cur = cwacc[k][h * 32 + i];
                    cur.x += acc[i].x; cur.y += acc[i].y;
                    cur.z += acc[i].z; cur.w += acc[i].w;
                    cwacc[k][h * 32 + i] = cur;
                }
            }
        }
        __syncthreads();
    }

    const float* accf = (const float*)cwacc;   // row stride 260 words
    float* dst = pS1 + (size_t)blockIdx.x * (32 * 256);
    #pragma unroll 8
    for (int i = 0; i < 32; ++i) {
        dst[i * 256 + t] = accf[i * 260 + t];
    }
    if (t < 32) {
        pW[blockIdx.x * 32 + t] =
            wsum_lds[0][t] + wsum_lds[1][t] + wsum_lds[2][t] + wsum_lds[3][t];
    }
}

template<int BPB>
__global__ void enc_reduce(const float* __restrict__ pS1, const float* __restrict__ pW,
                           const float* __restrict__ cw, float* __restrict__ enc)
{
    const int row = blockIdx.x;        // 0..511 = b*32 + k
    const int b = row >> 5;
    const int k = row & 31;
    const int c = threadIdx.x;
    float s = 0.f;
    #pragma unroll
    for (int jj = 0; jj < BPB; ++jj)
        s += pS1[((size_t)(b * BPB + jj)) * 8192 + k * 256 + c];
    float wsum = 0.f;
    #pragma unroll
    for (int jj = 0; jj < BPB; ++jj)
        wsum += pW[(b * BPB + jj) * 32 + k];
    enc[row * 256 + c] = s - wsum * cw[k * 256 + c];
}

__global__ void enc_stats(const float* __restrict__ enc, float* __restrict__ pstats)
{
    const int p = blockIdx.x;   // 16 blocks, 32 rows each
    const int c = threadIdx.x;
    float s = 0.f, ss = 0.f;
    #pragma unroll
    for (int r = 0; r < 32; ++r) {
        float v = enc[(p * 32 + r) * 256 + c];
        s += v;
        ss = fmaf(v, v, ss);
    }
    pstats[p * 512 + c] = s;
    pstats[p * 512 + 256 + c] = ss;
}

__global__ void enc_out(const float* __restrict__ enc, const float* __restrict__ pstats,
                        const float* __restrict__ gamma, const float* __restrict__ beta,
                        float* __restrict__ out)
{
    const int b = blockIdx.x;   // 16 blocks
    const int c = threadIdx.x;
    float s = 0.f, ss = 0.f;
    #pragma unroll
    for (int p = 0; p < 16; ++p) {
        s += pstats[p * 512 + c];
        ss += pstats[p * 512 + 256 + c];
    }
    const float mean = s * (1.f / 512.f);
    const float var = ss * (1.f / 512.f) - mean * mean;
    const float rstd = rsqrtf(var + BN_EPS);
    const float g = gamma[c] * rstd;
    const float bt = beta[c];
    float o = 0.f;
    #pragma unroll
    for (int k = 0; k < 32; ++k) {
        float e = enc[(b * 32 + k) * 256 + c];
        float v = (e - mean) * g + bt;
        o += fmaxf(v, 0.f);
    }
    out[b * 256 + c] = o;
}

template<int BPB>
static void launch_all(const float* x, const float* cw, const float* sf,
                       const float* gamma, const float* beta, float* out,
                       float* ws, hipStream_t stream)
{
    const int NB = 16 * BPB;
    float* pS1 = ws;
    float* pW = pS1 + (size_t)NB * 8192;
    float* enc = pW + (size_t)NB * 32;
    float* pstats = enc + 512 * 256;
    enc_main<BPB><<<NB, 256, 0, stream>>>(x, cw, sf, pS1, pW);
    enc_reduce<BPB><<<512, 256, 0, stream>>>(pS1, pW, cw, enc);
    enc_stats<<<16, 256, 0, stream>>>(enc, pstats);
    enc_out<<<16, 256, 0, stream>>>(enc, pstats, gamma, beta, out);
}

extern "C" void kernel_launch(void* const* d_in, const int* in_sizes, int n_in,
                              void* d_out, int out_size, void* d_ws, size_t ws_size,
                              hipStream_t stream) {
    const float* x     = (const float*)d_in[0];
    const float* cw    = (const float*)d_in[1];
    const float* sf    = (const float*)d_in[2];
    const float* gamma = (const float*)d_in[3];
    const float* beta  = (const float*)d_in[4];
    float* out = (float*)d_out;
    float* ws  = (float*)d_ws;

    const size_t need32 = ((size_t)512 * 8192 + 512 * 32 + 512 * 256 + 16 * 512) * 4;
    const size_t need16 = ((size_t)256 * 8192 + 256 * 32 + 512 * 256 + 16 * 512) * 4;

    if (ws_size >= need32)      launch_all<32>(x, cw, sf, gamma, beta, out, ws, stream);
    else if (ws_size >= need16) launch_all<16>(x, cw, sf, gamma, beta, out, ws, stream);
    else                        launch_all<8> (x, cw, sf, gamma, beta, out, ws, stream);
}

// Round 2
// 45.180 us; speedup vs baseline: 1.9049x; 1.9049x over previous
//
#include <hip/hip_runtime.h>
#include <hip/hip_bf16.h>

// Encoder: B=16, n=1024, C=256, K=32, fp32.
// sqnorm[n,k] = xx[n] - 2*dot[n,k] + cc[k];  dot = x . cw  (bf16 MFMA)
// w = softmax_k(sf[k]*sqnorm);  enc = S1 - wsum*cw;  S1 = sum_n w*x (fp32 VALU)
// out[b,c] = sum_k relu((enc-mean)*rsqrt(var+eps)*gamma + beta)

#define BN_EPS 1e-3f

typedef __attribute__((ext_vector_type(8))) short short8;
typedef __attribute__((ext_vector_type(4))) float f32x4;

static __device__ inline unsigned short f2bf(float f) {
    unsigned int u = __float_as_uint(f);
    unsigned int r = (u + 0x7fffu + ((u >> 16) & 1u)) >> 16;
    return (unsigned short)r;
}

static __device__ inline short8 pack8(float4 u, float4 v) {
    short8 r;
    r[0] = (short)f2bf(u.x); r[1] = (short)f2bf(u.y);
    r[2] = (short)f2bf(u.z); r[3] = (short)f2bf(u.w);
    r[4] = (short)f2bf(v.x); r[5] = (short)f2bf(v.y);
    r[6] = (short)f2bf(v.z); r[7] = (short)f2bf(v.w);
    return r;
}

// ---------------- MFMA main kernel: BPB=32 (512 blocks, 256 thr) -------------
__global__ __launch_bounds__(256, 2) void enc_main_mfma(
    const float* __restrict__ x, const float* __restrict__ cw,
    const float* __restrict__ sf, float* __restrict__ pS1, float* __restrict__ pW)
{
    const int b = blockIdx.x >> 5;
    const int jb = blockIdx.x & 31;
    const int t = threadIdx.x;
    const int w = t >> 6;
    const int lane = t & 63;

    __shared__ float4 xs4[32][65];          // x tile [32 pos][256 ch], stride 260 fp32
    __shared__ float4 dred[2][2][2][64];    // [Mtile][chHalf][Ntile][lane]
    __shared__ float  xxr[2][2][16];        // [Mtile][chHalf][posLocal]
    __shared__ float  ccred[8][32];
    __shared__ float  cc_lds[32];
    __shared__ float  sf_lds[32];
    __shared__ float  w_lds[32][33];        // [pos][k]
    __shared__ float  wsum_lds[4][32];

    // ---- stage x tile + cc partials + sf ----
    const int nbase = jb * 32;
    const float4* gx = (const float4*)(x + (size_t)b * 1024 * 256) + (size_t)nbase * 64;
    {
        const int p = t >> 3, q = t & 7;
        #pragma unroll
        for (int j = 0; j < 8; ++j)
            xs4[p][q + 8 * j] = gx[p * 64 + q + 8 * j];
    }
    {
        const int k = t & 31, seg = t >> 5;
        const float4* cw4 = (const float4*)cw;
        float s = 0.f;
        #pragma unroll
        for (int j = 0; j < 8; ++j) {
            float4 cv = cw4[k * 64 + seg * 8 + j];
            s += cv.x * cv.x + cv.y * cv.y + cv.z * cv.z + cv.w * cv.w;
        }
        ccred[seg][k] = s;
    }
    if (t < 32) sf_lds[t] = sf[t];
    __syncthreads();

    // ---- MFMA distance phase: wave = (Mtile = w>>1, chHalf = w&1) ----
    const int mt = w >> 1, half = w & 1;
    const int lrow = lane & 15;
    const int lk8 = (lane >> 4) * 8;
    const float* xsf = (const float*)xs4;

    {
        f32x4 D0 = {0.f, 0.f, 0.f, 0.f}, D1 = {0.f, 0.f, 0.f, 0.f};
        float xxp = 0.f;
        #pragma unroll
        for (int ks = 0; ks < 4; ++ks) {
            const int ch = half * 128 + ks * 32 + lk8;
            const float* ap = xsf + (mt * 16 + lrow) * 260 + ch;
            float4 u = *(const float4*)ap;
            float4 v = *(const float4*)(ap + 4);
            xxp += u.x * u.x + u.y * u.y + u.z * u.z + u.w * u.w
                 + v.x * v.x + v.y * v.y + v.z * v.z + v.w * v.w;
            short8 a = pack8(u, v);
            const float* b0p = cw + lrow * 256 + ch;
            const float* b1p = cw + (16 + lrow) * 256 + ch;
            short8 b0 = pack8(*(const float4*)b0p, *(const float4*)(b0p + 4));
            short8 b1 = pack8(*(const float4*)b1p, *(const float4*)(b1p + 4));
            D0 = __builtin_amdgcn_mfma_f32_16x16x32_bf16(a, b0, D0, 0, 0, 0);
            D1 = __builtin_amdgcn_mfma_f32_16x16x32_bf16(a, b1, D1, 0, 0, 0);
        }
        xxp += __shfl_xor(xxp, 16, 64);
        xxp += __shfl_xor(xxp, 32, 64);
        if (lane < 16) xxr[mt][half][lane] = xxp;
        dred[mt][half][0][lane] = make_float4(D0[0], D0[1], D0[2], D0[3]);
        dred[mt][half][1][lane] = make_float4(D1[0], D1[1], D1[2], D1[3]);
    }
    if (t < 32) {
        float s = 0.f;
        #pragma unroll
        for (int j = 0; j < 8; ++j) s += ccred[j][t];
        cc_lds[t] = s;
    }
    __syncthreads();

    // ---- softmax over k (waves 0,2 write w_lds for their Mtile) ----
    {
        float4 a0 = dred[mt][0][0][lane], b0 = dred[mt][1][0][lane];
        float4 a1 = dred[mt][0][1][lane], b1 = dred[mt][1][1][lane];
        float d0[4] = {a0.x + b0.x, a0.y + b0.y, a0.z + b0.z, a0.w + b0.w};
        float d1[4] = {a1.x + b1.x, a1.y + b1.y, a1.z + b1.z, a1.w + b1.w};
        const int k0 = lane & 15, k1 = 16 + k0;
        const float sf0 = sf_lds[k0], sf1 = sf_lds[k1];
        const float cc0 = cc_lds[k0], cc1 = cc_lds[k1];
        #pragma unroll
        for (int r = 0; r < 4; ++r) {
            const int pl = (lane >> 4) * 4 + r;
            const float xxv = xxr[mt][0][pl] + xxr[mt][1][pl];
            float s0 = sf0 * (xxv - 2.f * d0[r] + cc0);
            float s1 = sf1 * (xxv - 2.f * d1[r] + cc1);
            float m = fmaxf(s0, s1);
            #pragma unroll
            for (int msk = 1; msk <= 8; msk <<= 1) m = fmaxf(m, __shfl_xor(m, msk, 64));
            float e0 = __expf(s0 - m), e1 = __expf(s1 - m);
            float sm = e0 + e1;
            #pragma unroll
            for (int msk = 1; msk <= 8; msk <<= 1) sm += __shfl_xor(sm, msk, 64);
            const float inv = 1.f / sm;
            if (half == 0) {
                w_lds[mt * 16 + pl][k0] = e0 * inv;
                w_lds[mt * 16 + pl][k1] = e1 * inv;
            }
        }
    }
    __syncthreads();

    // ---- fp32 register accumulation (proven structure) ----
    const int h = lane >> 5;
    const int k = lane & 31;
    float4 acc[32];
    #pragma unroll
    for (int i = 0; i < 32; ++i) acc[i] = make_float4(0.f, 0.f, 0.f, 0.f);
    float wsum = 0.f;

    #pragma unroll 2
    for (int p8 = 0; p8 < 8; ++p8) {
        const int p = w * 8 + p8;
        const float wgt = w_lds[p][k];
        wsum += wgt;
        #pragma unroll
        for (int i = 0; i < 32; ++i) {
            float4 xv = xs4[p][h * 32 + i];
            acc[i].x = fmaf(wgt, xv.x, acc[i].x);
            acc[i].y = fmaf(wgt, xv.y, acc[i].y);
            acc[i].z = fmaf(wgt, xv.z, acc[i].z);
            acc[i].w = fmaf(wgt, xv.w, acc[i].w);
        }
    }
    if (h == 0) wsum_lds[w][k] = wsum;
    __syncthreads();   // xs4 becomes the merge buffer (x reads done)

    #pragma unroll
    for (int r = 0; r < 4; ++r) {
        const int q = (w + r) & 3;
        if ((k >> 3) == q) {
            #pragma unroll
            for (int i = 0; i < 32; ++i) {
                if (r == 0) {
                    xs4[k][h * 32 + i] = acc[i];
                } else {
                    float4 cur = xs4[k][h * 32 + i];
                    cur.x += acc[i].x; cur.y += acc[i].y;
                    cur.z += acc[i].z; cur.w += acc[i].w;
                    xs4[k][h * 32 + i] = cur;
                }
            }
        }
        __syncthreads();
    }

    const float* accf = (const float*)xs4;
    float* dst = pS1 + (size_t)blockIdx.x * (32 * 256);
    #pragma unroll 8
    for (int i = 0; i < 32; ++i) dst[i * 256 + t] = accf[i * 260 + t];
    if (t < 32)
        pW[blockIdx.x * 32 + t] =
            wsum_lds[0][t] + wsum_lds[1][t] + wsum_lds[2][t] + wsum_lds[3][t];
}

// ---------------- legacy VALU main kernel (ws fallback only) -----------------
template<int BPB>
__global__ __launch_bounds__(256, 2) void enc_main_valu(
    const float* __restrict__ x, const float* __restrict__ cw,
    const float* __restrict__ sf, float* __restrict__ pS1, float* __restrict__ pW)
{
    constexpr int POSB = 1024 / BPB;
    constexpr int PPW  = POSB / 4;
    constexpr int PAIRS = PPW / 2;

    const int b = blockIdx.x / BPB;
    const int j = blockIdx.x % BPB;
    const int t = threadIdx.x;
    const int w = t >> 6;
    const int lane = t & 63;
    const int h = lane >> 5;
    const int k = lane & 31;

    __shared__ float4 cwacc[32][65];
    __shared__ float4 xs4[4][2][64];
    __shared__ float  wsum_lds[4][32];

    for (int i = t; i < 2048; i += 256) cwacc[i >> 6][i & 63] = ((const float4*)cw)[i];
    const float sfk = sf[k];
    __syncthreads();

    float4 acc[32];
    #pragma unroll
    for (int i = 0; i < 32; ++i) acc[i] = make_float4(0.f, 0.f, 0.f, 0.f);
    float wsum = 0.f;

    const float* xb = x + (size_t)b * 1024 * 256;
    const int nbase = j * POSB + w * PPW;

    #pragma unroll 1
    for (int pr = 0; pr < PAIRS; ++pr) {
        const int n0 = nbase + pr * 2;
        float4 v0 = ((const float4*)(xb + (size_t)n0 * 256))[lane];
        float4 v1 = ((const float4*)(xb + (size_t)(n0 + 1) * 256))[lane];
        xs4[w][0][lane] = v0;
        xs4[w][1][lane] = v1;

        float sq0 = 0.f, sq1 = 0.f, sq2 = 0.f, sq3 = 0.f;
        #pragma unroll
        for (int ci = 0; ci < 64; ++ci) {
            float4 cv = cwacc[k][ci];
            float4 xv = xs4[w][h][ci];
            float d0 = xv.x - cv.x, d1 = xv.y - cv.y;
            float d2 = xv.z - cv.z, d3 = xv.w - cv.w;
            sq0 = fmaf(d0, d0, sq0); sq1 = fmaf(d1, d1, sq1);
            sq2 = fmaf(d2, d2, sq2); sq3 = fmaf(d3, d3, sq3);
        }
        float s = sfk * ((sq0 + sq1) + (sq2 + sq3));
        float m = s;
        #pragma unroll
        for (int d = 1; d <= 16; d <<= 1) m = fmaxf(m, __shfl_xor(m, d, 64));
        float e = __expf(s - m);
        float ssum = e;
        #pragma unroll
        for (int d = 1; d <= 16; d <<= 1) ssum += __shfl_xor(ssum, d, 64);
        float wgt = e / ssum;
        wsum += wgt;

        float wo = __shfl_xor(wgt, 32, 64);
        float w0 = h ? wo : wgt;
        float w1 = h ? wgt : wo;
        #pragma unroll
        for (int i = 0; i < 32; ++i) {
            float4 x0 = xs4[w][0][h * 32 + i];
            float4 x1 = xs4[w][1][h * 32 + i];
            acc[i].x = fmaf(w0, x0.x, fmaf(w1, x1.x, acc[i].x));
            acc[i].y = fmaf(w0, x0.y, fmaf(w1, x1.y, acc[i].y));
            acc[i].z = fmaf(w0, x0.z, fmaf(w1, x1.z, acc[i].z));
            acc[i].w = fmaf(w0, x0.w, fmaf(w1, x1.w, acc[i].w));
        }
    }

    float wtot = wsum + __shfl_xor(wsum, 32, 64);
    if (h == 0) wsum_lds[w][k] = wtot;
    __syncthreads();

    #pragma unroll
    for (int r = 0; r < 4; ++r) {
        const int q = (w + r) & 3;
        if ((k >> 3) == q) {
            #pragma unroll
            for (int i = 0; i < 32; ++i) {
                if (r == 0) {
                    cwacc[k][h * 32 + i] = acc[i];
                } else {
                    float4 cur = cwacc[k][h * 32 + i];
                    cur.x += acc[i].x; cur.y += acc[i].y;
                    cur.z += acc[i].z; cur.w += acc[i].w;
                    cwacc[k][h * 32 + i] = cur;
                }
            }
        }
        __syncthreads();
    }

    const float* accf = (const float*)cwacc;
    float* dst = pS1 + (size_t)blockIdx.x * (32 * 256);
    #pragma unroll 8
    for (int i = 0; i < 32; ++i) dst[i * 256 + t] = accf[i * 260 + t];
    if (t < 32)
        pW[blockIdx.x * 32 + t] =
            wsum_lds[0][t] + wsum_lds[1][t] + wsum_lds[2][t] + wsum_lds[3][t];
}

// ---------------- reduce / stats / out ----------------
template<int BPB>
__global__ void enc_reduce(const float* __restrict__ pS1, const float* __restrict__ pW,
                           const float* __restrict__ cw, float* __restrict__ enc)
{
    const int row = blockIdx.x;
    const int b = row >> 5;
    const int k = row & 31;
    const int c = threadIdx.x;
    float s = 0.f;
    #pragma unroll
    for (int jj = 0; jj < BPB; ++jj)
        s += pS1[((size_t)(b * BPB + jj)) * 8192 + k * 256 + c];
    float wsum = 0.f;
    #pragma unroll
    for (int jj = 0; jj < BPB; ++jj)
        wsum += pW[(b * BPB + jj) * 32 + k];
    enc[row * 256 + c] = s - wsum * cw[k * 256 + c];
}

__global__ void enc_stats(const float* __restrict__ enc, float* __restrict__ pstats)
{
    const int p = blockIdx.x;
    const int c = threadIdx.x;
    float s = 0.f, ss = 0.f;
    #pragma unroll
    for (int r = 0; r < 32; ++r) {
        float v = enc[(p * 32 + r) * 256 + c];
        s += v;
        ss = fmaf(v, v, ss);
    }
    pstats[p * 512 + c] = s;
    pstats[p * 512 + 256 + c] = ss;
}

__global__ void enc_out(const float* __restrict__ enc, const float* __restrict__ pstats,
                        const float* __restrict__ gamma, const float* __restrict__ beta,
                        float* __restrict__ out)
{
    const int b = blockIdx.x;
    const int c = threadIdx.x;
    float s = 0.f, ss = 0.f;
    #pragma unroll
    for (int p = 0; p < 16; ++p) {
        s += pstats[p * 512 + c];
        ss += pstats[p * 512 + 256 + c];
    }
    const float mean = s * (1.f / 512.f);
    const float var = ss * (1.f / 512.f) - mean * mean;
    const float rstd = rsqrtf(var + BN_EPS);
    const float g = gamma[c] * rstd;
    const float bt = beta[c];
    float o = 0.f;
    #pragma unroll
    for (int kk = 0; kk < 32; ++kk) {
        float e = enc[(b * 32 + kk) * 256 + c];
        float v = (e - mean) * g + bt;
        o += fmaxf(v, 0.f);
    }
    out[b * 256 + c] = o;
}

template<int BPB>
static void launch_valu(const float* x, const float* cw, const float* sf,
                        const float* gamma, const float* beta, float* out,
                        float* ws, hipStream_t stream)
{
    const int NB = 16 * BPB;
    float* pS1 = ws;
    float* pW = pS1 + (size_t)NB * 8192;
    float* enc = pW + (size_t)NB * 32;
    float* pstats = enc + 512 * 256;
    enc_main_valu<BPB><<<NB, 256, 0, stream>>>(x, cw, sf, pS1, pW);
    enc_reduce<BPB><<<512, 256, 0, stream>>>(pS1, pW, cw, enc);
    enc_stats<<<16, 256, 0, stream>>>(enc, pstats);
    enc_out<<<16, 256, 0, stream>>>(enc, pstats, gamma, beta, out);
}

extern "C" void kernel_launch(void* const* d_in, const int* in_sizes, int n_in,
                              void* d_out, int out_size, void* d_ws, size_t ws_size,
                              hipStream_t stream) {
    const float* x     = (const float*)d_in[0];
    const float* cw    = (const float*)d_in[1];
    const float* sf    = (const float*)d_in[2];
    const float* gamma = (const float*)d_in[3];
    const float* beta  = (const float*)d_in[4];
    float* out = (float*)d_out;
    float* ws  = (float*)d_ws;

    const size_t need32 = ((size_t)512 * 8192 + 512 * 32 + 512 * 256 + 16 * 512) * 4;
    const size_t need16 = ((size_t)256 * 8192 + 256 * 32 + 512 * 256 + 16 * 512) * 4;

    if (ws_size >= need32) {
        float* pS1 = ws;
        float* pW = pS1 + (size_t)512 * 8192;
        float* enc = pW + (size_t)512 * 32;
        float* pstats = enc + 512 * 256;
        enc_main_mfma<<<512, 256, 0, stream>>>(x, cw, sf, pS1, pW);
        enc_reduce<32><<<512, 256, 0, stream>>>(pS1, pW, cw, enc);
        enc_stats<<<16, 256, 0, stream>>>(enc, pstats);
        enc_out<<<16, 256, 0, stream>>>(enc, pstats, gamma, beta, out);
    } else if (ws_size >= need16) {
        launch_valu<16>(x, cw, sf, gamma, beta, out, ws, stream);
    } else {
        launch_valu<8>(x, cw, sf, gamma, beta, out, ws, stream);
    }
}

// Round 3
// 38.439 us; speedup vs baseline: 2.2390x; 1.1754x over previous
//
#include <hip/hip_runtime.h>
#include <hip/hip_bf16.h>

// Encoder: B=16, n=1024, C=256, K=32, fp32 in/out.
// GEMM1 (MFMA): dot[n,k] = x.cw^T ; sqnorm = xx - 2 dot + cc (fp32 softmax args)
// w = softmax_k(sf*sqnorm)
// GEMM2 (MFMA): S1[k,c] = sum_n w[n,k] x[n,c]  (bf16 in, fp32 accum)
// enc = S1 - wsum*cw;  out[b,c] = sum_k relu((enc-mean)*rsqrt(var+eps)*gamma+beta)

#define BN_EPS 1e-3f

typedef __attribute__((ext_vector_type(8))) short short8;
typedef __attribute__((ext_vector_type(4))) float f32x4;

static __device__ inline unsigned short f2bf(float f) {
    unsigned int u = __float_as_uint(f);
    unsigned int r = (u + 0x7fffu + ((u >> 16) & 1u)) >> 16;
    return (unsigned short)r;
}

static __device__ inline short8 pack8(float4 u, float4 v) {
    short8 r;
    r[0] = (short)f2bf(u.x); r[1] = (short)f2bf(u.y);
    r[2] = (short)f2bf(u.z); r[3] = (short)f2bf(u.w);
    r[4] = (short)f2bf(v.x); r[5] = (short)f2bf(v.y);
    r[6] = (short)f2bf(v.z); r[7] = (short)f2bf(v.w);
    return r;
}

#if __has_builtin(__builtin_amdgcn_global_load_lds)
#define HAVE_GLOAD_LDS 1
typedef const __attribute__((address_space(1))) void* as1_cvp;
typedef __attribute__((address_space(3))) void* as3_vp;
static __device__ inline void gload_lds16(const void* g, void* s) {
    __builtin_amdgcn_global_load_lds((as1_cvp)g, (as3_vp)s, 16, 0, 0);
}
#else
#define HAVE_GLOAD_LDS 0
#endif

// ---------------- MFMA main kernel: BPB=32 (512 blocks, 256 thr) -------------
__global__ __launch_bounds__(256, 2) void enc_main_mfma(
    const float* __restrict__ x, const float* __restrict__ cw,
    const float* __restrict__ sf, float* __restrict__ pS1, float* __restrict__ pW)
{
    const int b = blockIdx.x >> 5;
    const int jb = blockIdx.x & 31;
    const int t = threadIdx.x;
    const int w = t >> 6;
    const int lane = t & 63;

    __shared__ float4 xs4[32][65];           // x tile fp32, row = 65 float4 (1040B)
    __shared__ unsigned short xbf[32][272];  // x tile bf16 (row 544B, 16B aligned)
    __shared__ unsigned short wT[32][40];    // w^T bf16 [k][n], row 80B
    __shared__ float4 dred[2][2][2][64];     // [Mtile][chHalf][Ntile][lane]
    __shared__ float  xxr[2][2][16];
    __shared__ float  ccred[8][32];
    __shared__ float  cc_lds[32];
    __shared__ float  sf_lds[32];
    __shared__ float  w_lds[32][33];         // fp32 w [pos][k] (for wsum)

    // ---- phase 0: stage x (async DMA), cc partials, sf ----
    const int nbase = jb * 32;
    const float4* gx4 = (const float4*)(x + (size_t)b * 1024 * 256) + (size_t)nbase * 64;
#if HAVE_GLOAD_LDS
    #pragma unroll
    for (int i = 0; i < 8; ++i) {
        const int row = w * 8 + i;
        gload_lds16(gx4 + row * 64 + lane, &xs4[row][0]);
    }
#else
    {
        const int p = t >> 3, q = t & 7;
        #pragma unroll
        for (int j = 0; j < 8; ++j)
            xs4[p][q + 8 * j] = gx4[p * 64 + q + 8 * j];
    }
#endif
    {
        const int k = t >> 3, seg = t & 7;   // thread covers cw[k][seg*32 .. +31]
        const float4* cw4 = (const float4*)cw;
        float s = 0.f;
        #pragma unroll
        for (int j = 0; j < 8; ++j) {
            float4 cv = cw4[k * 64 + seg * 8 + j];
            s += cv.x * cv.x + cv.y * cv.y + cv.z * cv.z + cv.w * cv.w;
        }
        ccred[seg][k] = s;
    }
    if (t < 32) sf_lds[t] = sf[t];
    __syncthreads();

    // ---- phase 1: GEMM1 dot = x.cw^T ; also materialize xbf ----
    const int mt = w >> 1, half = w & 1;
    const int lrow = lane & 15;
    const int lk8 = (lane >> 4) * 8;
    const float* xsf = (const float*)xs4;

    {
        f32x4 D0 = {0.f, 0.f, 0.f, 0.f}, D1 = {0.f, 0.f, 0.f, 0.f};
        float xxp = 0.f;
        #pragma unroll
        for (int ks = 0; ks < 4; ++ks) {
            const int ch = half * 128 + ks * 32 + lk8;
            const int row = mt * 16 + lrow;
            const float* ap = xsf + row * 260 + ch;
            float4 u = *(const float4*)ap;
            float4 v = *(const float4*)(ap + 4);
            xxp += u.x * u.x + u.y * u.y + u.z * u.z + u.w * u.w
                 + v.x * v.x + v.y * v.y + v.z * v.z + v.w * v.w;
            short8 a = pack8(u, v);
            *(short8*)&xbf[row][ch] = a;     // bf16 x for GEMM2 (quadrant-owned)
            const float* b0p = cw + lrow * 256 + ch;
            const float* b1p = cw + (16 + lrow) * 256 + ch;
            short8 b0 = pack8(*(const float4*)b0p, *(const float4*)(b0p + 4));
            short8 b1 = pack8(*(const float4*)b1p, *(const float4*)(b1p + 4));
            D0 = __builtin_amdgcn_mfma_f32_16x16x32_bf16(a, b0, D0, 0, 0, 0);
            D1 = __builtin_amdgcn_mfma_f32_16x16x32_bf16(a, b1, D1, 0, 0, 0);
        }
        xxp += __shfl_xor(xxp, 16, 64);
        xxp += __shfl_xor(xxp, 32, 64);
        if (lane < 16) xxr[mt][half][lane] = xxp;
        dred[mt][half][0][lane] = make_float4(D0[0], D0[1], D0[2], D0[3]);
        dred[mt][half][1][lane] = make_float4(D1[0], D1[1], D1[2], D1[3]);
    }
    if (t < 32) {
        float s = 0.f;
        #pragma unroll
        for (int j = 0; j < 8; ++j) s += ccred[j][t];
        cc_lds[t] = s;
    }
    __syncthreads();

    // ---- phase 2: softmax over k; write w_lds fp32 + wT bf16 ----
    {
        float4 a0 = dred[mt][0][0][lane], b0 = dred[mt][1][0][lane];
        float4 a1 = dred[mt][0][1][lane], b1 = dred[mt][1][1][lane];
        float d0[4] = {a0.x + b0.x, a0.y + b0.y, a0.z + b0.z, a0.w + b0.w};
        float d1[4] = {a1.x + b1.x, a1.y + b1.y, a1.z + b1.z, a1.w + b1.w};
        const int k0 = lane & 15, k1 = 16 + k0;
        const float sf0 = sf_lds[k0], sf1 = sf_lds[k1];
        const float cc0 = cc_lds[k0], cc1 = cc_lds[k1];
        #pragma unroll
        for (int r = 0; r < 4; ++r) {
            const int pl = (lane >> 4) * 4 + r;
            const float xxv = xxr[mt][0][pl] + xxr[mt][1][pl];
            float s0 = sf0 * (xxv - 2.f * d0[r] + cc0);
            float s1 = sf1 * (xxv - 2.f * d1[r] + cc1);
            float m = fmaxf(s0, s1);
            #pragma unroll
            for (int msk = 1; msk <= 8; msk <<= 1) m = fmaxf(m, __shfl_xor(m, msk, 64));
            float e0 = __expf(s0 - m), e1 = __expf(s1 - m);
            float sm = e0 + e1;
            #pragma unroll
            for (int msk = 1; msk <= 8; msk <<= 1) sm += __shfl_xor(sm, msk, 64);
            const float inv = 1.f / sm;
            if (half == 0) {
                const int n = mt * 16 + pl;
                const float w0 = e0 * inv, w1 = e1 * inv;
                w_lds[n][k0] = w0;
                w_lds[n][k1] = w1;
                wT[k0][n] = f2bf(w0);
                wT[k1][n] = f2bf(w1);
            }
        }
    }
    __syncthreads();

    // ---- phase 3: GEMM2 S1 = w^T . x ; write pS1 + pW ----
    {
        const int g = lane >> 4;
        short8 a0 = *(const short8*)&wT[lrow][8 * g];
        short8 a1 = *(const short8*)&wT[16 + lrow][8 * g];
        f32x4 E00 = {0,0,0,0}, E01 = {0,0,0,0}, E02 = {0,0,0,0}, E03 = {0,0,0,0};
        f32x4 E10 = {0,0,0,0}, E11 = {0,0,0,0}, E12 = {0,0,0,0}, E13 = {0,0,0,0};
        const int cbase = w * 64;
        const unsigned short* xbu = &xbf[0][0];
        #pragma unroll
        for (int nt = 0; nt < 4; ++nt) {
            const int c = cbase + nt * 16 + lrow;
            short8 bf;
            #pragma unroll
            for (int e = 0; e < 8; ++e)
                bf[e] = (short)xbu[(8 * g + e) * 272 + c];
            if (nt == 0) { E00 = __builtin_amdgcn_mfma_f32_16x16x32_bf16(a0, bf, E00, 0,0,0);
                           E10 = __builtin_amdgcn_mfma_f32_16x16x32_bf16(a1, bf, E10, 0,0,0); }
            if (nt == 1) { E01 = __builtin_amdgcn_mfma_f32_16x16x32_bf16(a0, bf, E01, 0,0,0);
                           E11 = __builtin_amdgcn_mfma_f32_16x16x32_bf16(a1, bf, E11, 0,0,0); }
            if (nt == 2) { E02 = __builtin_amdgcn_mfma_f32_16x16x32_bf16(a0, bf, E02, 0,0,0);
                           E12 = __builtin_amdgcn_mfma_f32_16x16x32_bf16(a1, bf, E12, 0,0,0); }
            if (nt == 3) { E03 = __builtin_amdgcn_mfma_f32_16x16x32_bf16(a0, bf, E03, 0,0,0);
                           E13 = __builtin_amdgcn_mfma_f32_16x16x32_bf16(a1, bf, E13, 0,0,0); }
        }
        float* dst = pS1 + (size_t)blockIdx.x * 8192;
        const int krow = 4 * g;
        #pragma unroll
        for (int reg = 0; reg < 4; ++reg) {
            const int k0r = (krow + reg) * 256;
            const int k1r = (16 + krow + reg) * 256;
            dst[k0r + cbase +  0 + lrow] = E00[reg];
            dst[k0r + cbase + 16 + lrow] = E01[reg];
            dst[k0r + cbase + 32 + lrow] = E02[reg];
            dst[k0r + cbase + 48 + lrow] = E03[reg];
            dst[k1r + cbase +  0 + lrow] = E10[reg];
            dst[k1r + cbase + 16 + lrow] = E11[reg];
            dst[k1r + cbase + 32 + lrow] = E12[reg];
            dst[k1r + cbase + 48 + lrow] = E13[reg];
        }
    }
    if (t < 32) {
        float s = 0.f;
        #pragma unroll
        for (int p = 0; p < 32; ++p) s += w_lds[p][t];
        pW[blockIdx.x * 32 + t] = s;
    }
}

// ---------------- legacy VALU main kernel (ws fallback only) -----------------
template<int BPB>
__global__ __launch_bounds__(256, 2) void enc_main_valu(
    const float* __restrict__ x, const float* __restrict__ cw,
    const float* __restrict__ sf, float* __restrict__ pS1, float* __restrict__ pW)
{
    constexpr int POSB = 1024 / BPB;
    constexpr int PPW  = POSB / 4;
    constexpr int PAIRS = PPW / 2;

    const int b = blockIdx.x / BPB;
    const int j = blockIdx.x % BPB;
    const int t = threadIdx.x;
    const int w = t >> 6;
    const int lane = t & 63;
    const int h = lane >> 5;
    const int k = lane & 31;

    __shared__ float4 cwacc[32][65];
    __shared__ float4 xs4[4][2][64];
    __shared__ float  wsum_lds[4][32];

    for (int i = t; i < 2048; i += 256) cwacc[i >> 6][i & 63] = ((const float4*)cw)[i];
    const float sfk = sf[k];
    __syncthreads();

    float4 acc[32];
    #pragma unroll
    for (int i = 0; i < 32; ++i) acc[i] = make_float4(0.f, 0.f, 0.f, 0.f);
    float wsum = 0.f;

    const float* xb = x + (size_t)b * 1024 * 256;
    const int nb = j * POSB + w * PPW;

    #pragma unroll 1
    for (int pr = 0; pr < PAIRS; ++pr) {
        const int n0 = nb + pr * 2;
        float4 v0 = ((const float4*)(xb + (size_t)n0 * 256))[lane];
        float4 v1 = ((const float4*)(xb + (size_t)(n0 + 1) * 256))[lane];
        xs4[w][0][lane] = v0;
        xs4[w][1][lane] = v1;

        float sq0 = 0.f, sq1 = 0.f, sq2 = 0.f, sq3 = 0.f;
        #pragma unroll
        for (int ci = 0; ci < 64; ++ci) {
            float4 cv = cwacc[k][ci];
            float4 xv = xs4[w][h][ci];
            float d0 = xv.x - cv.x, d1 = xv.y - cv.y;
            float d2 = xv.z - cv.z, d3 = xv.w - cv.w;
            sq0 = fmaf(d0, d0, sq0); sq1 = fmaf(d1, d1, sq1);
            sq2 = fmaf(d2, d2, sq2); sq3 = fmaf(d3, d3, sq3);
        }
        float s = sfk * ((sq0 + sq1) + (sq2 + sq3));
        float m = s;
        #pragma unroll
        for (int d = 1; d <= 16; d <<= 1) m = fmaxf(m, __shfl_xor(m, d, 64));
        float e = __expf(s - m);
        float ssum = e;
        #pragma unroll
        for (int d = 1; d <= 16; d <<= 1) ssum += __shfl_xor(ssum, d, 64);
        float wgt = e / ssum;
        wsum += wgt;

        float wo = __shfl_xor(wgt, 32, 64);
        float w0 = h ? wo : wgt;
        float w1 = h ? wgt : wo;
        #pragma unroll
        for (int i = 0; i < 32; ++i) {
            float4 x0 = xs4[w][0][h * 32 + i];
            float4 x1 = xs4[w][1][h * 32 + i];
            acc[i].x = fmaf(w0, x0.x, fmaf(w1, x1.x, acc[i].x));
            acc[i].y = fmaf(w0, x0.y, fmaf(w1, x1.y, acc[i].y));
            acc[i].z = fmaf(w0, x0.z, fmaf(w1, x1.z, acc[i].z));
            acc[i].w = fmaf(w0, x0.w, fmaf(w1, x1.w, acc[i].w));
        }
    }

    float wtot = wsum + __shfl_xor(wsum, 32, 64);
    if (h == 0) wsum_lds[w][k] = wtot;
    __syncthreads();

    #pragma unroll
    for (int r = 0; r < 4; ++r) {
        const int q = (w + r) & 3;
        if ((k >> 3) == q) {
            #pragma unroll
            for (int i = 0; i < 32; ++i) {
                if (r == 0) {
                    xs4_dummy:;
                    cwacc[k][h * 32 + i] = acc[i];
                } else {
                    float4 cur = cwacc[k][h * 32 + i];
                    cur.x += acc[i].x; cur.y += acc[i].y;
                    cur.z += acc[i].z; cur.w += acc[i].w;
                    cwacc[k][h * 32 + i] = cur;
                }
            }
        }
        __syncthreads();
    }

    const float* accf = (const float*)cwacc;
    float* dst = pS1 + (size_t)blockIdx.x * (32 * 256);
    #pragma unroll 8
    for (int i = 0; i < 32; ++i) dst[i * 256 + t] = accf[i * 260 + t];
    if (t < 32)
        pW[blockIdx.x * 32 + t] =
            wsum_lds[0][t] + wsum_lds[1][t] + wsum_lds[2][t] + wsum_lds[3][t];
}

// ---------------- reduce / fused stats+out ----------------
template<int BPB>
__global__ void enc_reduce(const float* __restrict__ pS1, const float* __restrict__ pW,
                           const float* __restrict__ cw, float* __restrict__ enc)
{
    const int row = blockIdx.x;
    const int b = row >> 5;
    const int k = row & 31;
    const int c = threadIdx.x;
    float s = 0.f;
    #pragma unroll
    for (int jj = 0; jj < BPB; ++jj)
        s += pS1[((size_t)(b * BPB + jj)) * 8192 + k * 256 + c];
    float wsum = 0.f;
    #pragma unroll
    for (int jj = 0; jj < BPB; ++jj)
        wsum += pW[(b * BPB + jj) * 32 + k];
    enc[row * 256 + c] = s - wsum * cw[k * 256 + c];
}

__global__ void enc_out_fused(const float* __restrict__ enc,
                              const float* __restrict__ gamma,
                              const float* __restrict__ beta,
                              float* __restrict__ out)
{
    __shared__ float sred[2][256];
    __shared__ float ssred[2][256];
    const int t = threadIdx.x;
    const int c = t & 255;
    const int part = t >> 8;
    const int b = blockIdx.x;

    float s = 0.f, ss = 0.f;
    #pragma unroll 8
    for (int r = part * 256; r < part * 256 + 256; ++r) {
        float v = enc[r * 256 + c];
        s += v;
        ss = fmaf(v, v, ss);
    }
    sred[part][c] = s;
    ssred[part][c] = ss;
    __syncthreads();

    if (t < 256) {
        const float S = sred[0][c] + sred[1][c];
        const float SS = ssred[0][c] + ssred[1][c];
        const float mean = S * (1.f / 512.f);
        const float var = SS * (1.f / 512.f) - mean * mean;
        const float g = gamma[c] * rsqrtf(var + BN_EPS);
        const float bt = beta[c];
        float o = 0.f;
        #pragma unroll
        for (int k = 0; k < 32; ++k) {
            float e = enc[(b * 32 + k) * 256 + c];
            float v = (e - mean) * g + bt;
            o += fmaxf(v, 0.f);
        }
        out[b * 256 + c] = o;
    }
}

extern "C" void kernel_launch(void* const* d_in, const int* in_sizes, int n_in,
                              void* d_out, int out_size, void* d_ws, size_t ws_size,
                              hipStream_t stream) {
    const float* x     = (const float*)d_in[0];
    const float* cw    = (const float*)d_in[1];
    const float* sf    = (const float*)d_in[2];
    const float* gamma = (const float*)d_in[3];
    const float* beta  = (const float*)d_in[4];
    float* out = (float*)d_out;
    float* ws  = (float*)d_ws;

    const size_t need32 = ((size_t)512 * 8192 + 512 * 32 + 512 * 256) * 4;
    const size_t need16 = ((size_t)256 * 8192 + 256 * 32 + 512 * 256) * 4;

    if (ws_size >= need32) {
        float* pS1 = ws;
        float* pW  = pS1 + (size_t)512 * 8192;
        float* enc = pW + (size_t)512 * 32;
        enc_main_mfma<<<512, 256, 0, stream>>>(x, cw, sf, pS1, pW);
        enc_reduce<32><<<512, 256, 0, stream>>>(pS1, pW, cw, enc);
        enc_out_fused<<<16, 512, 0, stream>>>(enc, gamma, beta, out);
    } else if (ws_size >= need16) {
        float* pS1 = ws;
        float* pW  = pS1 + (size_t)256 * 8192;
        float* enc = pW + (size_t)256 * 32;
        enc_main_valu<16><<<256, 256, 0, stream>>>(x, cw, sf, pS1, pW);
        enc_reduce<16><<<512, 256, 0, stream>>>(pS1, pW, cw, enc);
        enc_out_fused<<<16, 512, 0, stream>>>(enc, gamma, beta, out);
    } else {
        float* pS1 = ws;
        float* pW  = pS1 + (size_t)128 * 8192;
        float* enc = pW + (size_t)128 * 32;
        enc_main_valu<8><<<128, 256, 0, stream>>>(x, cw, sf, pS1, pW);
        enc_reduce<8><<<512, 256, 0, stream>>>(pS1, pW, cw, enc);
        enc_out_fused<<<16, 512, 0, stream>>>(enc, gamma, beta, out);
    }
}